// Round 10
// baseline (35.331 us; speedup 1.0000x reference)
//
#include <hip/hip_runtime.h>
#include <hip/hip_bf16.h>
#include <math.h>

#define BB 4
#define CC 64
#define HID 32
#define NN 4096
#define LOG2E 1.44269504088896f

typedef short sh2 __attribute__((ext_vector_type(2)));
typedef short sh8 __attribute__((ext_vector_type(8)));
typedef float f2v __attribute__((ext_vector_type(2)));
typedef float f4v __attribute__((ext_vector_type(4)));

#define MFMA32(A,B,C) __builtin_amdgcn_mfma_f32_16x16x32_bf16(A,B,C,0,0,0)

__device__ __forceinline__ short f2b(float f) {
    __hip_bfloat16 h = __float2bfloat16(f);
    union { __hip_bfloat16 hb; short s; } u; u.hb = h; return u.s;
}
// cheap round-half-up bf16 (inputs are positive finite exp() values)
__device__ __forceinline__ short f2bh(float f) {
    union { float f; unsigned u; } u; u.f = f;
    return (short)((u.u + 0x8000u) >> 16);
}

__device__ __forceinline__ void gload_lds16(const short* g, short* l) {
    __builtin_amdgcn_global_load_lds(
        (const __attribute__((address_space(1))) unsigned int*)g,
        (__attribute__((address_space(3))) unsigned int*)l, 16, 0, 0);
}

// ---------------------------------------------------------------------------
// Kernel A: QKV projection -> bf16 Q[n][32] (pre-scaled by log2(e)),
// K[n][32], Vtp[32][n-permuted].  pos(key%32) = 8*((k>>2)&3)+(k&3)+4*(k>>4).
// ---------------------------------------------------------------------------
__global__ __launch_bounds__(1024) void qkv_kernel(
    const float* __restrict__ x,
    const float* __restrict__ wq, const float* __restrict__ bq,
    const float* __restrict__ wk, const float* __restrict__ bk,
    const float* __restrict__ wv, const float* __restrict__ bv,
    short* __restrict__ Qw, short* __restrict__ Kw, short* __restrict__ Vtp)
{
    __shared__ float xs[64][84];
    __shared__ float ws[96][84];
    __shared__ float bs[96];

    const int t  = threadIdx.x;
    const int b  = blockIdx.x >> 6;
    const int n0 = (blockIdx.x & 63) << 6;

    {
        int c = t >> 4, j4 = (t & 15) << 2;
        *(f4v*)&xs[c][j4] = *(const f4v*)(x + ((size_t)(b*CC + c))*NN + n0 + j4);
    }
    #pragma unroll
    for (int kl = 0; kl < 2; ++kl) {
        int idx = t + 1024*kl;
        if (idx < 1536) {
            int r = idx >> 4, c4 = (idx & 15) << 2;
            const float* src = (r < 32) ? (wq + r*CC + c4)
                             : (r < 64) ? (wk + (r-32)*CC + c4)
                                        : (wv + (r-64)*CC + c4);
            *(f4v*)&ws[r][c4] = *(const f4v*)src;
        }
    }
    if (t < 96) bs[t] = (t < 32) ? bq[t] : (t < 64) ? bk[t-32] : bv[t-64];
    __syncthreads();

    const int hg = t & 31;
    const int j0 = (t >> 5) << 1;

    float aq[2], ak[2], av[2];
    #pragma unroll
    for (int jj = 0; jj < 2; ++jj) { aq[jj]=bs[hg]; ak[jj]=bs[32+hg]; av[jj]=bs[64+hg]; }

    #pragma unroll
    for (int cs = 0; cs < 16; ++cs) {
        f4v wqv = *(f4v*)&ws[hg][cs*4];
        f4v wkv = *(f4v*)&ws[32+hg][cs*4];
        f4v wvv = *(f4v*)&ws[64+hg][cs*4];
        #pragma unroll
        for (int cc = 0; cc < 4; ++cc) {
            f2v xv = *(f2v*)&xs[cs*4+cc][j0];
            #pragma unroll
            for (int jj = 0; jj < 2; ++jj) {
                aq[jj] += wqv[cc]*xv[jj];
                ak[jj] += wkv[cc]*xv[jj];
                av[jj] += wvv[cc]*xv[jj];
            }
        }
    }

    const size_t nbase = (size_t)b*NN + n0 + j0;
    #pragma unroll
    for (int jj = 0; jj < 2; ++jj) {
        Qw[(nbase + jj)*HID + hg] = f2b(aq[jj] * LOG2E);
        Kw[(nbase + jj)*HID + hg] = f2b(ak[jj]);
    }
    const int w0  = j0 & 31;
    const int pos = 8*((w0 >> 2) & 3) + (w0 & 3) + 4*(w0 >> 4);
    sh2 vv; vv[0] = f2b(av[0]); vv[1] = f2b(av[1]);
    *(sh2*)(Vtp + ((size_t)b*HID + hg)*NN + n0 + (j0 & ~31) + pos) = vv;
}

// ---------------------------------------------------------------------------
// Kernel B: MFMA flash attention + projection + residual.
// 256 blocks x 1024 thr = 16 waves = 4 teams (key quarters) x 4 q-subtiles.
// Per team: 16 tiles of 64 keys, K/V double-buffered in LDS via
// global_load_lds (T3-minimal 2-phase: stage-next, read-cur, barrier).
// All LDS fragment reads are 1KB-contiguous (conflict-free by layout).
// ---------------------------------------------------------------------------
__global__ __launch_bounds__(1024, 4) void attn_kernel(
    const short* __restrict__ Qw, const short* __restrict__ Kw,
    const short* __restrict__ Vtp, const float* __restrict__ x,
    const float* __restrict__ wp, const float* __restrict__ bp,
    float* __restrict__ out)
{
    __shared__ short Kt[4][2][2048];   // [team][buf][key64 * d-slice] 32 KB
    __shared__ short Vt[4][2][2048];   // [team][buf][(h*2+G)*512 + d16*32 + g*8] 32 KB
    __shared__ float zr[4][64][33];    // 33.8 KB
    __shared__ float lr[4][64];        // 1 KB

    const int t    = threadIdx.x;
    const int b    = blockIdx.x >> 6;
    const int q0   = (blockIdx.x & 63) << 6;
    const int lane = t & 63;
    const int w    = t >> 6;
    const int T    = w >> 2;        // team: key quarter + epilogue channel block
    const int S    = w & 3;         // q-subtile
    const int g    = lane >> 4;
    const int qi   = lane & 15;
    const int k0   = T << 10;

    // Q B-fragment (k-order dims 8g..8g+7)
    const sh8 qf = *(const sh8*)(Qw + ((size_t)b*NN + q0 + S*16 + qi)*HID + 8*g);

    // hoisted epilogue operands, pinned live so they issue now (rule #17)
    const int qcol = q0 + S*16 + qi;
    float xres[4];
    #pragma unroll
    for (int r = 0; r < 4; ++r)
        xres[r] = x[((size_t)(b*CC + T*16 + 4*g + r))*NN + qcol];
    f4v wav = *(const f4v*)(wp + (T*16 + qi)*HID + 4*g);
    f4v wbv = *(const f4v*)(wp + (T*16 + qi)*HID + 16 + 4*g);
    f4v bpv = *(const f4v*)(bp + T*16 + 4*g);
    asm volatile("" :: "v"(xres[0]), "v"(xres[1]), "v"(xres[2]), "v"(xres[3]),
                       "v"(wav), "v"(wbv), "v"(bpv));

    // staging sources (per-lane); dest is wave-uniform + lane*16 (HW rule)
    const int kkey = (S*64 + lane) >> 2;               // key 0..63
    const int kg   = lane & 3;                         // d-slice
    const short* ksrc = Kw + ((size_t)b*NN + k0 + kkey)*HID + kg*8;
    const int vd = (lane >> 2) & 15;                   // d within half
    const short* vsrc = Vtp + ((size_t)b*HID + (S >> 1)*16 + vd)*NN
                      + k0 + (S & 1)*32 + (lane & 3)*8;

#define STAGE(bf, tt) do {                                         \
        gload_lds16(ksrc + (size_t)(tt)*64*HID, &Kt[T][bf][S*512]); \
        gload_lds16(vsrc + (tt)*64,             &Vt[T][bf][S*512]); \
    } while (0)

    const f4v zf = {0.f,0.f,0.f,0.f};
    f4v z0 = zf, z1 = zf;
    float lacc = 0.f;

    STAGE(0, 0);
    __syncthreads();

    for (int tt = 0; tt < 16; ++tt) {
        const int cur = tt & 1;
        if (tt < 15) STAGE(cur ^ 1, tt + 1);

        const short* Kb = &Kt[T][cur][0];
        const short* Vb = &Vt[T][cur][0];
        sh8 a00 = *(const sh8*)(Kb + (qi)*32      + g*8);   // keys  0-15
        sh8 a01 = *(const sh8*)(Kb + (16+qi)*32   + g*8);   // keys 16-31
        sh8 a10 = *(const sh8*)(Kb + (32+qi)*32   + g*8);   // keys 32-47
        sh8 a11 = *(const sh8*)(Kb + (48+qi)*32   + g*8);   // keys 48-63
        sh8 v00 = *(const sh8*)(Vb + 0*512  + qi*32 + g*8); // d 0-15,  G0
        sh8 v10 = *(const sh8*)(Vb + 1*512  + qi*32 + g*8); // d 0-15,  G1
        sh8 v01 = *(const sh8*)(Vb + 2*512  + qi*32 + g*8); // d 16-31, G0
        sh8 v11 = *(const sh8*)(Vb + 3*512  + qi*32 + g*8); // d 16-31, G1

        f4v s00 = MFMA32(a00, qf, zf);
        f4v s01 = MFMA32(a01, qf, zf);
        f4v s10 = MFMA32(a10, qf, zf);
        f4v s11 = MFMA32(a11, qf, zf);

        float e[16];
        #pragma unroll
        for (int r = 0; r < 4; ++r) {
            e[r]    = __builtin_amdgcn_exp2f(s00[r]);
            e[4+r]  = __builtin_amdgcn_exp2f(s01[r]);
            e[8+r]  = __builtin_amdgcn_exp2f(s10[r]);
            e[12+r] = __builtin_amdgcn_exp2f(s11[r]);
        }
        lacc += (((e[0]+e[1])+(e[2]+e[3])) + ((e[4]+e[5])+(e[6]+e[7])))
              + (((e[8]+e[9])+(e[10]+e[11])) + ((e[12]+e[13])+(e[14]+e[15])));

        sh8 p0, p1;
        #pragma unroll
        for (int j = 0; j < 8; ++j) { p0[j] = f2bh(e[j]); p1[j] = f2bh(e[8+j]); }

        z0 = MFMA32(v00, p0, z0);
        z1 = MFMA32(v01, p0, z1);
        z0 = MFMA32(v10, p1, z0);
        z1 = MFMA32(v11, p1, z1);

        __syncthreads();
    }
#undef STAGE

    lacc += __shfl_xor(lacc, 16, 64);
    lacc += __shfl_xor(lacc, 32, 64);

    *(f4v*)&zr[T][S*16 + qi][4*g]      = z0;
    *(f4v*)&zr[T][S*16 + qi][16 + 4*g] = z1;
    if (g == 0) lr[T][S*16 + qi] = lacc;
    __syncthreads();

    // every wave finalizes its (S) and projects its channel block ct = T
    const float lm = (lr[0][S*16+qi] + lr[1][S*16+qi])
                   + (lr[2][S*16+qi] + lr[3][S*16+qi]);
    f4v zm0 = zf, zm1 = zf;
    #pragma unroll
    for (int s = 0; s < 4; ++s) {
        zm0 += *(f4v*)&zr[s][S*16 + qi][4*g];
        zm1 += *(f4v*)&zr[s][S*16 + qi][16 + 4*g];
    }
    const float inv = 1.f / lm;
    sh8 pz;
    #pragma unroll
    for (int r = 0; r < 4; ++r) {
        pz[r]   = f2b(zm0[r]*inv);
        pz[4+r] = f2b(zm1[r]*inv);
    }
    sh8 af;
    #pragma unroll
    for (int i = 0; i < 4; ++i) { af[i] = f2b(wav[i]); af[4+i] = f2b(wbv[i]); }
    f4v cacc;
    #pragma unroll
    for (int r = 0; r < 4; ++r) cacc[r] = xres[r] + bpv[r];
    cacc = MFMA32(af, pz, cacc);
    #pragma unroll
    for (int r = 0; r < 4; ++r) {
        const int c = T*16 + 4*g + r;
        out[((size_t)(b*CC + c))*NN + qcol] = cacc[r];
    }
}

extern "C" void kernel_launch(void* const* d_in, const int* in_sizes, int n_in,
                              void* d_out, int out_size, void* d_ws, size_t ws_size,
                              hipStream_t stream) {
    const float* x  = (const float*)d_in[0];
    const float* wq = (const float*)d_in[1];
    const float* bq = (const float*)d_in[2];
    const float* wk = (const float*)d_in[3];
    const float* bk = (const float*)d_in[4];
    const float* wv = (const float*)d_in[5];
    const float* bv = (const float*)d_in[6];
    const float* wp = (const float*)d_in[7];
    const float* bp = (const float*)d_in[8];

    short* Qw  = (short*)d_ws;                       // bf16 [B][N][HID], pre-scaled log2(e)
    short* Kw  = Qw + (size_t)BB*NN*HID;             // bf16 [B][N][HID]
    short* Vtp = Kw + (size_t)BB*NN*HID;             // bf16 [B][HID][N-permuted]

    qkv_kernel<<<dim3(256), dim3(1024), 0, stream>>>(x, wq, bq, wk, bk, wv, bv, Qw, Kw, Vtp);
    attn_kernel<<<dim3(256), dim3(1024), 0, stream>>>(Qw, Kw, Vtp, x, wp, bp, (float*)d_out);
}